// Round 1
// baseline (140.947 us; speedup 1.0000x reference)
//
#include <hip/hip_runtime.h>
#include <hip/hip_bf16.h>

// B=4, S=256, H=768, P=54.
// out[b,i,j,p] = valid ? relu(ha[b,i]+hb[b,j]+bp1) . Wp2[p] + bp2[p] : 0
// valid = cand[i] & cand[j] & i!=j; cand = (relu(x W1^T + b1) . W2[0] + b2[0]) > 0.5
// cand rate ~1% -> sparse pairs.
// R3: 139.8us BEST (64x64 tile, 4x4 micro, KSPLIT=4). R6: coop fusion disaster.
// R7: re-anchor R3 + counter zeroing in gemm. 139.3us.
// R8: theory = gemm is LDS-port-bound (2 b128 reads / 16 FMA = 23us of LDS vs
//     7.7us VALU). (1) 128x128 tile, 8x8 micro as TWO stride-16B groups
//     (bank-conflict-free) -> 4 b128 / 64 FMA. KSPLIT=8 for occupancy.
//     (2) fold out-zeroing into pairs role; merge pairs+hab into one kernel.
//     6 dispatches -> 4, no out memset dispatch.

#define M_ROWS 1024
#define HDIM 768
#define PDIM 54
#define MAXC 256            // candidate slot cap (actual nc ~27)
#define KCHUNK 16
#define NKC (HDIM / KCHUNK) // 48
#define KSPLIT 8
#define KSEG (HDIM / KSPLIT) // 96

#define PAIRGRID 1024       // blocks 0..1023: zero-out + pair build
#define HABGRID  2048       // blocks 1024..3071: hab work

// ---- workspace layout (bytes) ----
#define CANDCNT_OFF  0
#define PAIRCNT_OFF  4
#define CANDIDX_OFF  8192        // MAXC int
#define CANDSLOT_OFF 12288       // 1024 int (fully written each call)
#define PAIR_OFF     16384       // up to 261120 int
#define HPART_OFF    1064960     // KSPLIT*1024*768 f32 = 24 MB

// ================= split-K GEMM =================
// 128x128 tile, K-seg 96, 256 thr, 8x8 micro (two 4-row/4-col groups).
// hpart[z][m][n] = partial x.W1^T. Block (0,0,0) threads 0/1 zero counters.
__global__ __launch_bounds__(256) void gemm_k_kernel(
    const float* __restrict__ x, const float* __restrict__ W1,
    float* __restrict__ hpart, int* __restrict__ counters)
{
    __shared__ float As[16][132];
    __shared__ float Bs[16][132];

    if (blockIdx.x == 0 && blockIdx.y == 0 && blockIdx.z == 0 && threadIdx.x < 2)
        counters[threadIdx.x] = 0;

    const int m0 = blockIdx.x * 128;
    const int n0 = blockIdx.y * 128;
    const int kb = blockIdx.z * KSEG;
    const int t  = threadIdx.x;
    const int tm = t & 15;        // 0..15 -> rows tm*4+i and 64+tm*4+i
    const int tn = t >> 4;        // 0..15 -> cols tn*4+j and 64+tn*4+j
    const int r  = t >> 2;        // 0..63
    const int c4 = (t & 3) * 4;   // 0,4,8,12

    float acc[8][8] = {};

    for (int k0 = kb; k0 < kb + KSEG; k0 += 16) {
        // stage 128 rows x 16 k of A and B (transposed into LDS)
        #pragma unroll
        for (int rr = 0; rr < 128; rr += 64) {
            float4 av = *(const float4*)(x  + (size_t)(m0 + rr + r) * HDIM + k0 + c4);
            float4 bv = *(const float4*)(W1 + (size_t)(n0 + rr + r) * HDIM + k0 + c4);
            As[c4+0][rr+r] = av.x; As[c4+1][rr+r] = av.y;
            As[c4+2][rr+r] = av.z; As[c4+3][rr+r] = av.w;
            Bs[c4+0][rr+r] = bv.x; Bs[c4+1][rr+r] = bv.y;
            Bs[c4+2][rr+r] = bv.z; Bs[c4+3][rr+r] = bv.w;
        }
        __syncthreads();
        #pragma unroll
        for (int kk = 0; kk < 16; ++kk) {
            float a[8], b[8];
            #pragma unroll
            for (int i = 0; i < 4; ++i) {
                a[i]     = As[kk][tm * 4 + i];
                a[i + 4] = As[kk][64 + tm * 4 + i];
                b[i]     = Bs[kk][tn * 4 + i];
                b[i + 4] = Bs[kk][64 + tn * 4 + i];
            }
            #pragma unroll
            for (int i = 0; i < 8; ++i)
                #pragma unroll
                for (int j = 0; j < 8; ++j)
                    acc[i][j] += a[i] * b[j];
        }
        __syncthreads();
    }

    float* dst = hpart + (size_t)blockIdx.z * (M_ROWS * HDIM);
    #pragma unroll
    for (int ii = 0; ii < 8; ++ii) {
        int row = m0 + (ii >> 2) * 64 + tm * 4 + (ii & 3);
        #pragma unroll
        for (int h = 0; h < 2; ++h) {
            float4 v = make_float4(acc[ii][h*4+0], acc[ii][h*4+1],
                                   acc[ii][h*4+2], acc[ii][h*4+3]);
            *(float4*)(dst + (size_t)row * HDIM + n0 + h * 64 + tn * 4) = v;
        }
    }
}

// reduce KSPLIT partials, relu.w2, decide cand. One block per row m.
__global__ __launch_bounds__(256) void span_cand_kernel(
    const float* __restrict__ hpart, const float* __restrict__ b1,
    const float* __restrict__ w2row, const float* __restrict__ b2,
    int* __restrict__ candCount, int* __restrict__ candIdx,
    int* __restrict__ candSlot)
{
    const int m = blockIdx.x;
    const int t = threadIdx.x;
    float p = 0.f;
    for (int n = t; n < HDIM; n += 256) {
        float v = 0.f;
        #pragma unroll
        for (int z = 0; z < KSPLIT; ++z)
            v += hpart[(size_t)z * (M_ROWS * HDIM) + (size_t)m * HDIM + n];
        v += b1[n];
        v = v > 0.f ? v : 0.f;
        p += v * w2row[n];
    }
    __shared__ float wred[4];
    #pragma unroll
    for (int off = 32; off > 0; off >>= 1) p += __shfl_down(p, off, 64);
    if ((t & 63) == 0) wred[t >> 6] = p;
    __syncthreads();
    if (t == 0) {
        float s = wred[0] + wred[1] + wred[2] + wred[3] + b2[0];
        if (s > 0.5f) {
            int sl = atomicAdd(candCount, 1);
            if (sl < MAXC) { candIdx[sl] = m; candSlot[m] = sl; }
            else candSlot[m] = -1;
        } else {
            candSlot[m] = -1;
        }
    }
}

// ================= merged: zero-out + pair build + hab =================
// blocks [0, PAIRGRID): zero this block's contiguous out range (256 idx * 54 f)
//                       then test its 256 (b,i,j) for validity -> pairList.
// blocks [PAIRGRID, PAIRGRID+HABGRID): hab work item = (slot, kc):
//                       ha/hb[slot][kc*16 .. +15] = x[row] . Wp1 chunk.
__global__ __launch_bounds__(256) void hab_pairs_kernel(
    const float* __restrict__ x, const float* __restrict__ Wp1,
    const int* __restrict__ candCount, const int* __restrict__ candIdx,
    float* __restrict__ ha, float* __restrict__ hb,
    const int* __restrict__ candSlot,
    int* __restrict__ pairCount, int* __restrict__ pairList,
    float* __restrict__ out)
{
    if (blockIdx.x < PAIRGRID) {
        // ---- zero role: 256*54 floats = 3456 float4, contiguous ----
        const int pb = blockIdx.x;
        float4* dst = (float4*)(out + (size_t)pb * 256 * PDIM);
        const float4 z4 = make_float4(0.f, 0.f, 0.f, 0.f);
        for (int f = threadIdx.x; f < 256 * PDIM / 4; f += 256)
            dst[f] = z4;
        // ---- pair build ----
        int idx = pb * 256 + threadIdx.x;
        int b = idx >> 16;
        int i = (idx >> 8) & 255;
        int j = idx & 255;
        if (i != j && candSlot[b * 256 + i] >= 0 && candSlot[b * 256 + j] >= 0) {
            int p = atomicAdd(pairCount, 1);
            pairList[p] = idx;
        }
        return;
    }

    // ---- hab role ----
    __shared__ float xs[HDIM];
    __shared__ float red[2][KCHUNK][17];
    int nc = *candCount; if (nc > MAXC) nc = MAXC;
    const int nitems = nc * NKC;
    const int kk  = threadIdx.x >> 4;
    const int hb0 = (threadIdx.x & 15) * 4;

    for (int item = blockIdx.x - PAIRGRID; item < nitems; item += HABGRID) {
        int slot = item / NKC;
        int kc   = item % NKC;
        int row  = candIdx[slot];

        for (int h = threadIdx.x; h < HDIM; h += 256)
            xs[h] = x[(size_t)row * HDIM + h];
        __syncthreads();

        int k = kc * KCHUNK + kk;
        const float* wr = Wp1 + (size_t)k * (2 * HDIM);
        float sa = 0.f, sb = 0.f;
        #pragma unroll
        for (int h = hb0; h < HDIM; h += 64) {
            float4 xv = *(const float4*)(xs + h);
            float4 wa = *(const float4*)(wr + h);
            float4 wb = *(const float4*)(wr + HDIM + h);
            sa += xv.x * wa.x + xv.y * wa.y + xv.z * wa.z + xv.w * wa.w;
            sb += xv.x * wb.x + xv.y * wb.y + xv.z * wb.z + xv.w * wb.w;
        }
        red[0][kk][threadIdx.x & 15] = sa;
        red[1][kk][threadIdx.x & 15] = sb;
        __syncthreads();

        if (threadIdx.x < 32) {
            int which = threadIdx.x >> 4;
            int kk2   = threadIdx.x & 15;
            float s = 0.f;
            #pragma unroll
            for (int g = 0; g < 16; ++g) s += red[which][kk2][g];
            float* dstp = which == 0 ? ha : hb;
            dstp[(size_t)slot * HDIM + kc * KCHUNK + kk2] = s;
        }
        __syncthreads();
    }
}

// ================= sparse pair logits =================
__global__ __launch_bounds__(256) void pair_kernel(
    const float* __restrict__ ha, const float* __restrict__ hb,
    const float* __restrict__ bp1, const float* __restrict__ Wp2,
    const float* __restrict__ bp2, const int* __restrict__ candSlot,
    const int* __restrict__ pairCount, const int* __restrict__ pairList,
    float* __restrict__ out)
{
    __shared__ float v[HDIM];
    __shared__ float red[4][PDIM + 2];
    const int np = *pairCount;
    const int t = threadIdx.x;
    for (int p = blockIdx.x; p < np; p += gridDim.x) {
        int idx = pairList[p];
        int b = idx >> 16;
        int i = (idx >> 8) & 255;
        int j = idx & 255;
        int si = candSlot[b * 256 + i];
        int sj = candSlot[b * 256 + j];
        if (t < 192) {
            float4 a4 = *(const float4*)(ha + (size_t)si * HDIM + t * 4);
            float4 b4 = *(const float4*)(hb + (size_t)sj * HDIM + t * 4);
            float4 c4 = *(const float4*)(bp1 + t * 4);
            float4 r;
            r.x = a4.x + b4.x + c4.x; r.x = r.x > 0.f ? r.x : 0.f;
            r.y = a4.y + b4.y + c4.y; r.y = r.y > 0.f ? r.y : 0.f;
            r.z = a4.z + b4.z + c4.z; r.z = r.z > 0.f ? r.z : 0.f;
            r.w = a4.w + b4.w + c4.w; r.w = r.w > 0.f ? r.w : 0.f;
            *(float4*)(v + t * 4) = r;
        }
        __syncthreads();
        if (t < 216) {
            int pp  = t % PDIM;
            int seg = t / PDIM;               // 0..3, h-range 192 each
            const float* w = Wp2 + (size_t)pp * HDIM + seg * 192;
            const float* vv = v + seg * 192;
            float s = 0.f;
            for (int h = 0; h < 192; h += 4) {
                float4 a = *(const float4*)(vv + h);
                float4 b2_ = *(const float4*)(w + h);
                s += a.x * b2_.x + a.y * b2_.y + a.z * b2_.z + a.w * b2_.w;
            }
            red[seg][pp] = s;
        }
        __syncthreads();
        if (t < PDIM)
            out[(size_t)idx * PDIM + t] = red[0][t] + red[1][t] + red[2][t] + red[3][t] + bp2[t];
        __syncthreads();
    }
}

extern "C" void kernel_launch(void* const* d_in, const int* in_sizes, int n_in,
                              void* d_out, int out_size, void* d_ws, size_t ws_size,
                              hipStream_t stream) {
    const float* x   = (const float*)d_in[0];
    const float* W1s = (const float*)d_in[1];
    const float* b1s = (const float*)d_in[2];
    const float* W2s = (const float*)d_in[3];
    const float* b2s = (const float*)d_in[4];
    const float* Wp1 = (const float*)d_in[5];
    const float* bp1 = (const float*)d_in[6];
    const float* Wp2 = (const float*)d_in[7];
    const float* bp2 = (const float*)d_in[8];

    char* ws = (char*)d_ws;
    int*   counters = (int*)(ws + CANDCNT_OFF);   // [0]=candCnt, [1]=pairCnt
    int*   candCnt  = counters;
    int*   pairCnt  = counters + 1;
    int*   candIdx  = (int*)(ws + CANDIDX_OFF);
    int*   candSlot = (int*)(ws + CANDSLOT_OFF);
    int*   pairList = (int*)(ws + PAIR_OFF);
    float* hpart    = (float*)(ws + HPART_OFF);
    float* ha       = hpart + (size_t)KSPLIT * M_ROWS * HDIM;
    float* hb       = ha + (size_t)MAXC * HDIM;
    float* out = (float*)d_out;

    dim3 g(M_ROWS / 128, HDIM / 128, KSPLIT);
    gemm_k_kernel<<<g, 256, 0, stream>>>(x, W1s, hpart, counters);

    span_cand_kernel<<<M_ROWS, 256, 0, stream>>>(hpart, b1s, W2s, b2s,
                                                 candCnt, candIdx, candSlot);

    hab_pairs_kernel<<<PAIRGRID + HABGRID, 256, 0, stream>>>(
        x, Wp1, candCnt, candIdx, ha, hb, candSlot, pairCnt, pairList, out);

    pair_kernel<<<512, 256, 0, stream>>>(ha, hb, bp1, Wp2, bp2,
                                         candSlot, pairCnt, pairList, out);
}

// Round 2
// 136.828 us; speedup vs baseline: 1.0301x; 1.0301x over previous
//
#include <hip/hip_runtime.h>
#include <hip/hip_bf16.h>

// B=4, S=256, H=768, P=54.
// out[b,i,j,p] = valid ? relu(ha[b,i]+hb[b,j]+bp1) . Wp2[p] + bp2[p] : 0
// valid = cand[i] & cand[j] & i!=j; cand = (relu(x W1^T + b1) . W2[0] + b2[0]) > 0.5
// cand rate ~1% -> sparse pairs. h is ONLY used for the threshold -> the span
// gemm gates a boolean; output precision comes from the fp32 pair path.
// R3: 139.8 (split-K VALU gemm + hpart). R7: 139.3. R8: 140.9 (128^2 gemm,
// KSPLIT=8, merged dispatches) - improvements never register, regressions do.
// R9: remove hpart round-trip entirely: full-K bf16x3 MFMA span gemm
//     (hi*hi+hi*lo+lo*hi, err ~1e-6 on span logit), relu+w2 fused in epilogue,
//     output = spanPart[12][1024] (48 KB, was 24 MB). 4 dispatches.

#define M_ROWS 1024
#define HDIM 768
#define PDIM 54
#define MAXC 256            // candidate slot cap (actual nc ~11-27)
#define KCHUNK 16
#define NKC (HDIM / KCHUNK) // 48
#define NB_N 12             // 768/64 n-tiles

#define PAIRGRID 1024       // blocks 0..1023: zero-out + pair build
#define HABGRID  2048       // blocks 1024..3071: hab work

// ---- workspace layout (bytes) ----
#define CANDCNT_OFF  0
#define CANDIDX_OFF  8192        // MAXC int
#define CANDSLOT_OFF 12288       // 1024 int (fully written each call)
#define PAIR_OFF     16384       // up to 261120 int
#define SPAN_OFF     1064960     // 12*1024 f32 spanPart, then ha, hb

typedef __attribute__((ext_vector_type(8))) short short8;
typedef __attribute__((ext_vector_type(4))) float f32x4;

static __device__ __forceinline__ unsigned short f2bf(float f) {
    unsigned u = __float_as_uint(f);
    u += 0x7fffu + ((u >> 16) & 1u);
    return (unsigned short)(u >> 16);
}
static __device__ __forceinline__ float bf2f(unsigned short h) {
    return __uint_as_float(((unsigned)h) << 16);
}
static __device__ __forceinline__ void cvt8(float4 p, float4 q,
                                            short8& hi, short8& lo) {
    float f[8] = {p.x, p.y, p.z, p.w, q.x, q.y, q.z, q.w};
    #pragma unroll
    for (int j = 0; j < 8; ++j) {
        unsigned short h = f2bf(f[j]);
        hi[j] = (short)h;
        lo[j] = (short)f2bf(f[j] - bf2f(h));
    }
}

// ================= full-K bf16x3 MFMA span gemm =================
// 64x64 tile, 4 waves (2x2), each wave 32x32 = 2x2 16x16x32 frags.
// C[m][n] = sum_k x[m][k]*W1[n][k]; epilogue: relu(C+b1).w2 row-reduced
// -> spanPart[nblk][m]. Register-double-buffered K loop (24 steps of 32).
// A-frag: lane holds x[row=m0+wseg+f*16+(l&15)][k0+(l>>4)*8 + j], j=0..7.
// B-frag: same pattern on W1 rows (B^T layout). C/D: row=(l>>4)*4+r, col=l&15.
__global__ __launch_bounds__(256) void mfma_span_kernel(
    const float* __restrict__ x, const float* __restrict__ W1,
    const float* __restrict__ b1, const float* __restrict__ w2row,
    float* __restrict__ spanPart, int* __restrict__ counters)
{
    if (blockIdx.x == 0 && blockIdx.y == 0 && threadIdx.x < 2)
        counters[threadIdx.x] = 0;

    const int t    = threadIdx.x;
    const int lane = t & 63;
    const int w    = t >> 6;
    const int wm   = w >> 1, wn = w & 1;
    const int l15  = lane & 15;
    const int lk   = (lane >> 4) * 8;
    const int m0   = blockIdx.x * 64;
    const int n0   = blockIdx.y * 64;

    const float* aBase = x  + (size_t)(m0 + wm * 32 + l15) * HDIM + lk;
    const float* bBase = W1 + (size_t)(n0 + wn * 32 + l15) * HDIM + lk;

    f32x4 acc00 = {0.f, 0.f, 0.f, 0.f};
    f32x4 acc01 = {0.f, 0.f, 0.f, 0.f};
    f32x4 acc10 = {0.f, 0.f, 0.f, 0.f};
    f32x4 acc11 = {0.f, 0.f, 0.f, 0.f};

    float4 ra0p_x, ra0q_x, ra1p_x, ra1q_x, rb0p_x, rb0q_x, rb1p_x, rb1q_x;
    float4 ra0p_y, ra0q_y, ra1p_y, ra1q_y, rb0p_y, rb0q_y, rb1p_y, rb1q_y;

#define LOADK(sfx, kk) { \
    ra0p##sfx = *(const float4*)(aBase + (kk));                 \
    ra0q##sfx = *(const float4*)(aBase + (kk) + 4);             \
    ra1p##sfx = *(const float4*)(aBase + 16 * HDIM + (kk));     \
    ra1q##sfx = *(const float4*)(aBase + 16 * HDIM + (kk) + 4); \
    rb0p##sfx = *(const float4*)(bBase + (kk));                 \
    rb0q##sfx = *(const float4*)(bBase + (kk) + 4);             \
    rb1p##sfx = *(const float4*)(bBase + 16 * HDIM + (kk));     \
    rb1q##sfx = *(const float4*)(bBase + 16 * HDIM + (kk) + 4); \
}

#define COMPUTE(sfx) { \
    short8 ah0, al0, ah1, al1, bh0, bl0, bh1, bl1;  \
    cvt8(ra0p##sfx, ra0q##sfx, ah0, al0);           \
    cvt8(ra1p##sfx, ra1q##sfx, ah1, al1);           \
    cvt8(rb0p##sfx, rb0q##sfx, bh0, bl0);           \
    cvt8(rb1p##sfx, rb1q##sfx, bh1, bl1);           \
    acc00 = __builtin_amdgcn_mfma_f32_16x16x32_bf16(ah0, bh0, acc00, 0, 0, 0); \
    acc00 = __builtin_amdgcn_mfma_f32_16x16x32_bf16(ah0, bl0, acc00, 0, 0, 0); \
    acc00 = __builtin_amdgcn_mfma_f32_16x16x32_bf16(al0, bh0, acc00, 0, 0, 0); \
    acc01 = __builtin_amdgcn_mfma_f32_16x16x32_bf16(ah0, bh1, acc01, 0, 0, 0); \
    acc01 = __builtin_amdgcn_mfma_f32_16x16x32_bf16(ah0, bl1, acc01, 0, 0, 0); \
    acc01 = __builtin_amdgcn_mfma_f32_16x16x32_bf16(al0, bh1, acc01, 0, 0, 0); \
    acc10 = __builtin_amdgcn_mfma_f32_16x16x32_bf16(ah1, bh0, acc10, 0, 0, 0); \
    acc10 = __builtin_amdgcn_mfma_f32_16x16x32_bf16(ah1, bl0, acc10, 0, 0, 0); \
    acc10 = __builtin_amdgcn_mfma_f32_16x16x32_bf16(al1, bh0, acc10, 0, 0, 0); \
    acc11 = __builtin_amdgcn_mfma_f32_16x16x32_bf16(ah1, bh1, acc11, 0, 0, 0); \
    acc11 = __builtin_amdgcn_mfma_f32_16x16x32_bf16(ah1, bl1, acc11, 0, 0, 0); \
    acc11 = __builtin_amdgcn_mfma_f32_16x16x32_bf16(al1, bh1, acc11, 0, 0, 0); \
}

    LOADK(_x, 0);
    for (int k = 0; k < HDIM; k += 64) {
        LOADK(_y, k + 32);
        COMPUTE(_x);
        if (k + 64 < HDIM) { LOADK(_x, k + 64); }
        COMPUTE(_y);
    }
#undef LOADK
#undef COMPUTE

    // epilogue: relu(acc + b1[n]) * w2[n], reduce over this block's 64 cols
    float sp0[4], sp1[4];
    #pragma unroll
    for (int r = 0; r < 4; ++r) { sp0[r] = 0.f; sp1[r] = 0.f; }

#define SPANACC(ACC, SP, J) { \
    _Pragma("unroll") \
    for (int r = 0; r < 4; ++r) { \
        int n = n0 + wn * 32 + (J) * 16 + l15; \
        float v = ACC[r] + b1[n]; \
        v = v > 0.f ? v : 0.f; \
        SP[r] += v * w2row[n]; \
    } \
}
    SPANACC(acc00, sp0, 0)
    SPANACC(acc01, sp0, 1)
    SPANACC(acc10, sp1, 0)
    SPANACC(acc11, sp1, 1)
#undef SPANACC

    __shared__ float red[64][2];
    #pragma unroll
    for (int r = 0; r < 4; ++r) {
        float v0 = sp0[r], v1 = sp1[r];
        #pragma unroll
        for (int msk = 1; msk < 16; msk <<= 1) {
            v0 += __shfl_xor(v0, msk, 64);
            v1 += __shfl_xor(v1, msk, 64);
        }
        if (l15 == 0) {
            int rr = (lane >> 4) * 4 + r;
            red[wm * 32 + rr][wn]      = v0;
            red[wm * 32 + 16 + rr][wn] = v1;
        }
    }
    __syncthreads();
    if (t < 64)
        spanPart[(size_t)blockIdx.y * M_ROWS + m0 + t] = red[t][0] + red[t][1];
}

// ================= candidate threshold (tiny) =================
__global__ __launch_bounds__(256) void cand_kernel(
    const float* __restrict__ spanPart, const float* __restrict__ b2,
    int* __restrict__ candCount, int* __restrict__ candIdx,
    int* __restrict__ candSlot)
{
    int m = blockIdx.x * 256 + threadIdx.x;
    float s = b2[0];
    #pragma unroll
    for (int nb = 0; nb < NB_N; ++nb) s += spanPart[(size_t)nb * M_ROWS + m];
    if (s > 0.5f) {
        int sl = atomicAdd(candCount, 1);
        if (sl < MAXC) { candIdx[sl] = m; candSlot[m] = sl; }
        else candSlot[m] = -1;
    } else {
        candSlot[m] = -1;
    }
}

// ================= merged: zero-out + pair build + hab (R8-proven) =========
__global__ __launch_bounds__(256) void hab_pairs_kernel(
    const float* __restrict__ x, const float* __restrict__ Wp1,
    const int* __restrict__ candCount, const int* __restrict__ candIdx,
    float* __restrict__ ha, float* __restrict__ hb,
    const int* __restrict__ candSlot,
    int* __restrict__ pairCount, int* __restrict__ pairList,
    float* __restrict__ out)
{
    if (blockIdx.x < PAIRGRID) {
        // ---- zero role: 256*54 floats = 3456 float4, contiguous ----
        const int pb = blockIdx.x;
        float4* dst = (float4*)(out + (size_t)pb * 256 * PDIM);
        const float4 z4 = make_float4(0.f, 0.f, 0.f, 0.f);
        for (int f = threadIdx.x; f < 256 * PDIM / 4; f += 256)
            dst[f] = z4;
        // ---- pair build ----
        int idx = pb * 256 + threadIdx.x;
        int b = idx >> 16;
        int i = (idx >> 8) & 255;
        int j = idx & 255;
        if (i != j && candSlot[b * 256 + i] >= 0 && candSlot[b * 256 + j] >= 0) {
            int p = atomicAdd(pairCount, 1);
            pairList[p] = idx;
        }
        return;
    }

    // ---- hab role ----
    __shared__ float xs[HDIM];
    __shared__ float red[2][KCHUNK][17];
    int nc = *candCount; if (nc > MAXC) nc = MAXC;
    const int nitems = nc * NKC;
    const int kk  = threadIdx.x >> 4;
    const int hb0 = (threadIdx.x & 15) * 4;

    for (int item = blockIdx.x - PAIRGRID; item < nitems; item += HABGRID) {
        int slot = item / NKC;
        int kc   = item % NKC;
        int row  = candIdx[slot];

        for (int h = threadIdx.x; h < HDIM; h += 256)
            xs[h] = x[(size_t)row * HDIM + h];
        __syncthreads();

        int k = kc * KCHUNK + kk;
        const float* wr = Wp1 + (size_t)k * (2 * HDIM);
        float sa = 0.f, sb = 0.f;
        #pragma unroll
        for (int h = hb0; h < HDIM; h += 64) {
            float4 xv = *(const float4*)(xs + h);
            float4 wa = *(const float4*)(wr + h);
            float4 wb = *(const float4*)(wr + HDIM + h);
            sa += xv.x * wa.x + xv.y * wa.y + xv.z * wa.z + xv.w * wa.w;
            sb += xv.x * wb.x + xv.y * wb.y + xv.z * wb.z + xv.w * wb.w;
        }
        red[0][kk][threadIdx.x & 15] = sa;
        red[1][kk][threadIdx.x & 15] = sb;
        __syncthreads();

        if (threadIdx.x < 32) {
            int which = threadIdx.x >> 4;
            int kk2   = threadIdx.x & 15;
            float s = 0.f;
            #pragma unroll
            for (int g = 0; g < 16; ++g) s += red[which][kk2][g];
            float* dstp = which == 0 ? ha : hb;
            dstp[(size_t)slot * HDIM + kc * KCHUNK + kk2] = s;
        }
        __syncthreads();
    }
}

// ================= sparse pair logits (R3-proven) =================
__global__ __launch_bounds__(256) void pair_kernel(
    const float* __restrict__ ha, const float* __restrict__ hb,
    const float* __restrict__ bp1, const float* __restrict__ Wp2,
    const float* __restrict__ bp2, const int* __restrict__ candSlot,
    const int* __restrict__ pairCount, const int* __restrict__ pairList,
    float* __restrict__ out)
{
    __shared__ float v[HDIM];
    __shared__ float red[4][PDIM + 2];
    const int np = *pairCount;
    const int t = threadIdx.x;
    for (int p = blockIdx.x; p < np; p += gridDim.x) {
        int idx = pairList[p];
        int b = idx >> 16;
        int i = (idx >> 8) & 255;
        int j = idx & 255;
        int si = candSlot[b * 256 + i];
        int sj = candSlot[b * 256 + j];
        if (t < 192) {
            float4 a4 = *(const float4*)(ha + (size_t)si * HDIM + t * 4);
            float4 b4 = *(const float4*)(hb + (size_t)sj * HDIM + t * 4);
            float4 c4 = *(const float4*)(bp1 + t * 4);
            float4 r;
            r.x = a4.x + b4.x + c4.x; r.x = r.x > 0.f ? r.x : 0.f;
            r.y = a4.y + b4.y + c4.y; r.y = r.y > 0.f ? r.y : 0.f;
            r.z = a4.z + b4.z + c4.z; r.z = r.z > 0.f ? r.z : 0.f;
            r.w = a4.w + b4.w + c4.w; r.w = r.w > 0.f ? r.w : 0.f;
            *(float4*)(v + t * 4) = r;
        }
        __syncthreads();
        if (t < 216) {
            int pp  = t % PDIM;
            int seg = t / PDIM;               // 0..3, h-range 192 each
            const float* w = Wp2 + (size_t)pp * HDIM + seg * 192;
            const float* vv = v + seg * 192;
            float s = 0.f;
            for (int h = 0; h < 192; h += 4) {
                float4 a = *(const float4*)(vv + h);
                float4 b2_ = *(const float4*)(w + h);
                s += a.x * b2_.x + a.y * b2_.y + a.z * b2_.z + a.w * b2_.w;
            }
            red[seg][pp] = s;
        }
        __syncthreads();
        if (t < PDIM)
            out[(size_t)idx * PDIM + t] = red[0][t] + red[1][t] + red[2][t] + red[3][t] + bp2[t];
        __syncthreads();
    }
}

extern "C" void kernel_launch(void* const* d_in, const int* in_sizes, int n_in,
                              void* d_out, int out_size, void* d_ws, size_t ws_size,
                              hipStream_t stream) {
    const float* x   = (const float*)d_in[0];
    const float* W1s = (const float*)d_in[1];
    const float* b1s = (const float*)d_in[2];
    const float* W2s = (const float*)d_in[3];
    const float* b2s = (const float*)d_in[4];
    const float* Wp1 = (const float*)d_in[5];
    const float* bp1 = (const float*)d_in[6];
    const float* Wp2 = (const float*)d_in[7];
    const float* bp2 = (const float*)d_in[8];

    char* ws = (char*)d_ws;
    int*   counters = (int*)(ws + CANDCNT_OFF);   // [0]=candCnt, [1]=pairCnt
    int*   candCnt  = counters;
    int*   pairCnt  = counters + 1;
    int*   candIdx  = (int*)(ws + CANDIDX_OFF);
    int*   candSlot = (int*)(ws + CANDSLOT_OFF);
    int*   pairList = (int*)(ws + PAIR_OFF);
    float* spanPart = (float*)(ws + SPAN_OFF);    // 12*1024 f32
    float* ha       = spanPart + (size_t)NB_N * M_ROWS;
    float* hb       = ha + (size_t)MAXC * HDIM;
    float* out = (float*)d_out;

    mfma_span_kernel<<<dim3(M_ROWS / 64, NB_N), 256, 0, stream>>>(
        x, W1s, b1s, W2s, spanPart, counters);

    cand_kernel<<<4, 256, 0, stream>>>(spanPart, b2s, candCnt, candIdx, candSlot);

    hab_pairs_kernel<<<PAIRGRID + HABGRID, 256, 0, stream>>>(
        x, Wp1, candCnt, candIdx, ha, hb, candSlot, pairCnt, pairList, out);

    pair_kernel<<<512, 256, 0, stream>>>(ha, hb, bp1, Wp2, bp2,
                                         candSlot, pairCnt, pairList, out);
}